// Round 8
// baseline (598.793 us; speedup 1.0000x reference)
//
#include <hip/hip_runtime.h>
#include <hip/hip_bf16.h>
#include <hip/hip_cooperative_groups.h>

namespace cg = cooperative_groups;

#define FIN   128
#define NH    8
#define NEG   0.2f
#define HB    128         // histogram/placement blocks (both paths)
#define NMAX  10240       // LDS cursor capacity (40 KB)
#define GW0   512         // first GEMM wave in coop P1 (block 128, disjoint from hist)
#define GRID  960         // coop grid: <= 4 blocks/CU * 256 CUs capacity, with margin
#define TPB   256

typedef __attribute__((ext_vector_type(8))) short short8;   // 8 bf16 in 4 VGPRs
typedef __attribute__((ext_vector_type(4))) float f32x4;

// ---- helpers ----
__device__ __forceinline__ short f2bf(float f) {            // fp32 -> bf16 bits, RNE
    unsigned u = __float_as_uint(f);
    return (short)((u + 0x7FFFu + ((u >> 16) & 1u)) >> 16);
}
__device__ __forceinline__ float bflo(unsigned p) { return __uint_as_float(p << 16); }
__device__ __forceinline__ float bfhi(unsigned p) { return __uint_as_float(p & 0xFFFF0000u); }
__device__ __forceinline__ float ld_f(const void* p, int i, bool bf16) {
    if (bf16) {
        unsigned h = ((const unsigned short*)p)[i];
        return __uint_as_float(h << 16);
    }
    return ((const float*)p)[i];
}
__device__ __forceinline__ short8 ld_frag(const void* p, size_t off, bool bf16) {
    if (bf16) return *(const short8*)((const short*)p + off);
    const float* f = (const float*)p + off;
    f32x4 f0 = *(const f32x4*)f;
    f32x4 f1 = *(const f32x4*)(f + 4);
    short8 r;
    r[0] = f2bf(f0[0]); r[1] = f2bf(f0[1]); r[2] = f2bf(f0[2]); r[3] = f2bf(f0[3]);
    r[4] = f2bf(f1[0]); r[5] = f2bf(f1[1]); r[6] = f2bf(f1[2]); r[7] = f2bf(f1[3]);
    return r;
}
__device__ __forceinline__ float escore(float ss, float st) {
    float v = ss + st;
    v = v > 0.f ? v : NEG * v;                // leaky relu
    return __expf(fminf(v, 60.f));            // shift-free softmax numerator
}
// Per-wave dtype probes. All 64 lanes of the calling wave must be active.
__device__ __forceinline__ bool wave_bf16(const unsigned* x32) {
    unsigned w  = x32[threadIdx.x & 63];
    unsigned ex = (w >> 7) & 0xFFu;           // bf16 exponent of x[2*lane] if packed
    return __popcll(__ballot(ex >= 118u && ex <= 130u)) >= 48;
}
__device__ __forceinline__ bool wave_e64(const int* e32) {
    return __popcll(__ballot(e32[2 * (threadIdx.x & 63) + 1] == 0)) == 64;
}

// ---- GEMM role body (shared by coop + fallback) ----
__device__ __forceinline__ void gemm_tile(
    int wt, int halfTiles, const void* x, const void* Wp, const void* Ws,
    const void* ssrcw, const void* stgtw,
    unsigned short* projb, unsigned short* skipb, float* s_src, float* s_tgt)
{
    const bool bf16 = wave_bf16((const unsigned*)x);
    const int lane = threadIdx.x & 63;
    const int mat = (wt >= halfTiles) ? 1 : 0;
    const int m0 = (mat ? wt - halfTiles : wt) * 16;
    const int mr = lane & 15;
    const int kb = lane >> 4;

    short8 a[4];
    const size_t xoff = (size_t)(m0 + mr) * FIN + kb * 8;
#pragma unroll
    for (int s = 0; s < 4; ++s) a[s] = ld_frag(x, xoff + s * 32, bf16);

    const void* W = mat ? Ws : Wp;
    f32x4 acc[8];
#pragma unroll
    for (int c = 0; c < 8; ++c) {
        acc[c] = (f32x4){0.f, 0.f, 0.f, 0.f};
        const size_t woff = (size_t)(c * 16 + mr) * FIN + kb * 8;
#pragma unroll
        for (int s = 0; s < 4; ++s) {
            short8 b = ld_frag(W, woff + s * 32, bf16);
            acc[c] = __builtin_amdgcn_mfma_f32_16x16x32_bf16(a[s], b, acc[c], 0, 0, 0);
        }
    }
    // D layout: col = lane&15, row = (lane>>4)*4 + r   [verified m89]
    if (mat == 0) {
#pragma unroll
        for (int c = 0; c < 8; ++c) {
            float sw = ld_f(ssrcw, c * 16 + mr, bf16);
            float tw = ld_f(stgtw, c * 16 + mr, bf16);
#pragma unroll
            for (int r = 0; r < 4; ++r) {
                int row = m0 + kb * 4 + r;
                float v = acc[c][r];
                projb[(size_t)row * FIN + c * 16 + mr] = (unsigned short)f2bf(v);
                float vs = v * sw, vt = v * tw;
#pragma unroll
                for (int o = 8; o >= 1; o >>= 1) {
                    vs += __shfl_xor(vs, o);
                    vt += __shfl_xor(vt, o);
                }
                if (mr == 0) {
                    s_src[row * NH + c] = vs;
                    s_tgt[row * NH + c] = vt;
                }
            }
        }
    } else {
#pragma unroll
        for (int c = 0; c < 8; ++c)
#pragma unroll
            for (int r = 0; r < 4; ++r)
                skipb[(size_t)(m0 + kb * 4 + r) * FIN + c * 16 + mr] =
                    (unsigned short)f2bf(acc[c][r]);
    }
}

// ---- aggregate role body (shared by coop + fallback) ----
__device__ __forceinline__ void agg_node(
    int n, bool bf16, const int* offs, const int* sorted_src,
    const float* s_src, const float* s_tgt,
    const unsigned short* projb, const unsigned short* skipb,
    const void* bias, void* out)
{
    const int l = threadIdx.x & 63;
    const int start = offs[n], end = offs[n + 1];
    const int h = l >> 3;
    const int c2 = l * 2;
    const float st = s_tgt[(size_t)n * NH + h];

    float ae0 = 0.f, ao0 = 0.f, ae1 = 0.f, ao1 = 0.f;
    float ae2 = 0.f, ao2 = 0.f, ae3 = 0.f, ao3 = 0.f;
    float d0 = 0.f, d1 = 0.f, d2 = 0.f, d3 = 0.f;
    int e = start;
    for (; e + 4 <= end; e += 4) {
        int s0 = sorted_src[e],     s1 = sorted_src[e + 1];
        int s2 = sorted_src[e + 2], s3 = sorted_src[e + 3];
        float w0 = escore(s_src[(size_t)s0 * NH + h], st);
        float w1 = escore(s_src[(size_t)s1 * NH + h], st);
        float w2 = escore(s_src[(size_t)s2 * NH + h], st);
        float w3 = escore(s_src[(size_t)s3 * NH + h], st);
        unsigned p0 = *(const unsigned*)(projb + (size_t)s0 * FIN + c2);
        unsigned p1 = *(const unsigned*)(projb + (size_t)s1 * FIN + c2);
        unsigned p2 = *(const unsigned*)(projb + (size_t)s2 * FIN + c2);
        unsigned p3 = *(const unsigned*)(projb + (size_t)s3 * FIN + c2);
        ae0 += w0 * bflo(p0); ao0 += w0 * bfhi(p0); d0 += w0;
        ae1 += w1 * bflo(p1); ao1 += w1 * bfhi(p1); d1 += w1;
        ae2 += w2 * bflo(p2); ao2 += w2 * bfhi(p2); d2 += w2;
        ae3 += w3 * bflo(p3); ao3 += w3 * bfhi(p3); d3 += w3;
    }
    for (; e < end; ++e) {
        int s = sorted_src[e];
        float w = escore(s_src[(size_t)s * NH + h], st);
        unsigned p = *(const unsigned*)(projb + (size_t)s * FIN + c2);
        ae0 += w * bflo(p); ao0 += w * bfhi(p); d0 += w;
    }

    float inv = 1.f / (((d0 + d1) + (d2 + d3)) + 1e-16f);
    unsigned skp = *(const unsigned*)(skipb + (size_t)n * FIN + c2);
    float be, bo;
    if (bf16) {
        unsigned bb = *(const unsigned*)((const unsigned short*)bias + c2);
        be = bflo(bb); bo = bfhi(bb);
    } else {
        float2 b2 = *(const float2*)((const float*)bias + c2);
        be = b2.x; bo = b2.y;
    }
    float oe = ((ae0 + ae1) + (ae2 + ae3)) * inv + bflo(skp) + be;
    float oo = ((ao0 + ao1) + (ao2 + ao3)) * inv + bfhi(skp) + bo;
    if (bf16) {
        unsigned pr = ((unsigned)(unsigned short)f2bf(oo) << 16)
                    | (unsigned)(unsigned short)f2bf(oe);
        ((unsigned*)out)[((size_t)n * FIN + c2) >> 1] = pr;
    } else {
        float2 o2; o2.x = oe; o2.y = oo;
        *(float2*)((float*)out + (size_t)n * FIN + c2) = o2;
    }
}

// ================= single cooperative kernel: all 5 phases =================
__global__ __launch_bounds__(TPB, 4) void k_gat(
    const void* __restrict__ x, const void* __restrict__ Wp,
    const void* __restrict__ Ws, const void* __restrict__ ssrcw,
    const void* __restrict__ stgtw, const void* __restrict__ bias,
    const int* __restrict__ e32, void* __restrict__ out,
    unsigned short* __restrict__ projb, unsigned short* __restrict__ skipb,
    float* __restrict__ s_src, float* __restrict__ s_tgt,
    int* __restrict__ sorted_src, int* __restrict__ offs,
    int* __restrict__ tmp_off, int* __restrict__ bt,
    int* __restrict__ hist2d, int* __restrict__ pbase,
    int N, int E, int perB, int tiles, int halfTiles)
{
    cg::grid_group grid = cg::this_grid();
    __shared__ int sh[NMAX];                 // 40 KB, reused per phase
    const int b = blockIdx.x, t = threadIdx.x;
    const int wv = b * 4 + (t >> 6);

    // ---- P1: LDS histogram (blocks < HB)  ||  GEMM (waves GW0..GW0+tiles) ----
    if (b < HB) {
        const bool e64 = wave_e64(e32);
        unsigned* l32 = (unsigned*)sh;       // two 16-bit bins per word
        const int nw = (N + 1) >> 1;
        for (int j = t; j < nw; j += TPB) l32[j] = 0;
        __syncthreads();
        const int lo = b * perB, hi = min(lo + perB, E);
        for (int i = lo + t; i < hi; i += TPB) {
            int tg = e64 ? e32[2 * ((size_t)E + i)] : e32[(size_t)E + i];
            atomicAdd(&l32[tg >> 1], 1u << ((tg & 1) << 4));
        }
        __syncthreads();
        for (int j = t; j < N; j += TPB)
            hist2d[(size_t)b * N + j] = (l32[j >> 1] >> ((j & 1) << 4)) & 0xFFFFu;
    } else {
        const int wt = wv - GW0;
        if (wt >= 0 && wt < tiles)
            gemm_tile(wt, halfTiles, x, Wp, Ws, ssrcw, stgtw,
                      projb, skipb, s_src, s_tgt);
    }
    grid.sync();

    // ---- P2: per-bin scan over HB hist rows + per-chunk block scan ----
    const int CB = (N + TPB - 1) / TPB;
    if (b < CB) {
        const int j = b * TPB + t;
        int s = 0;
        if (j < N) {
            for (int r = 0; r < HB; ++r) {
                int v = hist2d[(size_t)r * N + j];
                pbase[(size_t)r * N + j] = s;
                s += v;
            }
        }
        sh[t] = s;
        __syncthreads();
#pragma unroll
        for (int off = 1; off < TPB; off <<= 1) {
            int add = (t >= off) ? sh[t - off] : 0;
            __syncthreads();
            sh[t] += add;
            __syncthreads();
        }
        int incl = sh[t];
        if (j < N) tmp_off[j] = incl - s;
        if (t == TPB - 1) bt[b] = incl;
    }
    grid.sync();

    // ---- P3: finalize offs (CB blocks; cheap) ----
    if (b < CB) {
        int carry = 0;
        for (int r = 0; r < b; ++r) carry += bt[r];
        const int j = b * TPB + t;
        if (j < N) offs[j] = tmp_off[j] + carry;
        if (b == CB - 1 && t == 0) offs[N] = carry + bt[b];
    }
    grid.sync();

    // ---- P4: placement via LDS cursors (blocks < HB) ----
    if (b < HB) {
        const bool e64 = wave_e64(e32);
        for (int j = t; j < N; j += TPB)
            sh[j] = offs[j] + pbase[(size_t)b * N + j];
        __syncthreads();
        const int lo = b * perB, hi = min(lo + perB, E);
        for (int i = lo + t; i < hi; i += TPB) {
            int s, tg;
            if (e64) { s = e32[2 * (size_t)i]; tg = e32[2 * ((size_t)E + i)]; }
            else     { s = e32[i];             tg = e32[(size_t)E + i]; }
            int pos = atomicAdd(&sh[tg], 1);   // LDS atomic
            sorted_src[pos] = s;
        }
    }
    grid.sync();

    // ---- P5: aggregate, one wave per node, grid-strided ----
    {
        const bool bf16 = wave_bf16((const unsigned*)x);
        const int TOTW = (int)gridDim.x * 4;
        for (int n = wv; n < N; n += TOTW)
            agg_node(n, bf16, offs, sorted_src, s_src, s_tgt,
                     projb, skipb, bias, out);
    }
}

// ================= fallback path (R7 5-kernel pipeline) =================
__global__ __launch_bounds__(256) void k_projhist(
    const void* __restrict__ x, const void* __restrict__ Wp,
    const void* __restrict__ Ws,
    const void* __restrict__ ssrcw, const void* __restrict__ stgtw,
    unsigned short* __restrict__ projb, unsigned short* __restrict__ skipb,
    float* __restrict__ s_src, float* __restrict__ s_tgt,
    const int* __restrict__ e32, int* __restrict__ hist2d,
    int N, int E, int tiles, int halfTiles, int projBlocks, int perB)
{
    __shared__ unsigned l32[NMAX / 2];
    if ((int)blockIdx.x >= projBlocks) {
        const bool e64 = wave_e64(e32);
        const int hb = (int)blockIdx.x - projBlocks;
        const int t = threadIdx.x;
        const int nw = (N + 1) >> 1;
        for (int j = t; j < nw; j += 256) l32[j] = 0;
        __syncthreads();
        const int lo = hb * perB;
        const int hi = min(lo + perB, E);
        for (int i = lo + t; i < hi; i += 256) {
            int tg = e64 ? e32[2 * ((size_t)E + i)] : e32[(size_t)E + i];
            atomicAdd(&l32[tg >> 1], 1u << ((tg & 1) << 4));
        }
        __syncthreads();
        for (int j = t; j < N; j += 256)
            hist2d[(size_t)hb * N + j] = (l32[j >> 1] >> ((j & 1) << 4)) & 0xFFFFu;
        return;
    }
    const int wt = blockIdx.x * 4 + (threadIdx.x >> 6);
    if (wt >= tiles) return;
    gemm_tile(wt, halfTiles, x, Wp, Ws, ssrcw, stgtw, projb, skipb, s_src, s_tgt);
}

__global__ __launch_bounds__(256) void k_colscan(
    const int* __restrict__ hist2d, int* __restrict__ pbase,
    int* __restrict__ cnt, int N)
{
    int j = blockIdx.x * 256 + threadIdx.x;
    if (j >= N) return;
    int s = 0;
#pragma unroll 4
    for (int b = 0; b < HB; ++b) {
        int v = hist2d[(size_t)b * N + j];
        pbase[(size_t)b * N + j] = s;
        s += v;
    }
    cnt[j] = s;
}

__global__ __launch_bounds__(256) void k_offscan(const int* __restrict__ cnt,
                                                 int* __restrict__ offs, int N)
{
    const int t = threadIdx.x;
    const int PER = (N + 255) / 256;
    const int base = t * PER;
    int local[40];
    int sum = 0;
    for (int i = 0; i < PER && i < 40; ++i) {
        int idx = base + i;
        int v = (idx < N) ? cnt[idx] : 0;
        local[i] = sum;
        sum += v;
    }
    __shared__ int sd[256];
    sd[t] = sum;
    __syncthreads();
#pragma unroll
    for (int off = 1; off < 256; off <<= 1) {
        int add = (t >= off) ? sd[t - off] : 0;
        __syncthreads();
        sd[t] += add;
        __syncthreads();
    }
    int excl = sd[t] - sum;
    for (int i = 0; i < PER && i < 40; ++i) {
        int idx = base + i;
        if (idx < N) offs[idx] = excl + local[i];
    }
    if (t == 255) offs[N] = sd[255];
}

__global__ __launch_bounds__(256) void k_place(
    const int* __restrict__ e32, const int* __restrict__ offs,
    const int* __restrict__ pbase, int* __restrict__ sorted_src,
    int N, int E, int perB)
{
    __shared__ int cur[NMAX];
    const bool e64 = wave_e64(e32);
    const int b = blockIdx.x, t = threadIdx.x;
    for (int j = t; j < N; j += 256)
        cur[j] = offs[j] + pbase[(size_t)b * N + j];
    __syncthreads();
    const int lo = b * perB;
    const int hi = min(lo + perB, E);
    for (int i = lo + t; i < hi; i += 256) {
        int s, tg;
        if (e64) { s = e32[2 * (size_t)i]; tg = e32[2 * ((size_t)E + i)]; }
        else     { s = e32[i];             tg = e32[(size_t)E + i]; }
        int pos = atomicAdd(&cur[tg], 1);
        sorted_src[pos] = s;
    }
}

__global__ __launch_bounds__(64) void k_aggregate(
    const int* __restrict__ offs, const int* __restrict__ sorted_src,
    const float* __restrict__ s_src, const float* __restrict__ s_tgt,
    const unsigned short* __restrict__ projb, const unsigned short* __restrict__ skipb,
    const void* __restrict__ bias, void* __restrict__ out,
    const unsigned* __restrict__ x32)
{
    const bool bf16 = wave_bf16(x32);
    agg_node(blockIdx.x, bf16, offs, sorted_src, s_src, s_tgt,
             projb, skipb, bias, out);
}

extern "C" void kernel_launch(void* const* d_in, const int* in_sizes, int n_in,
                              void* d_out, int out_size, void* d_ws, size_t ws_size,
                              hipStream_t stream)
{
    const void* x    = d_in[0];
    const int* edges = (const int*)d_in[1];
    const void* Wp   = d_in[2];
    const void* Ws   = d_in[3];
    const void* ssw  = d_in[4];
    const void* stw  = d_in[5];
    const void* bias = d_in[6];
    void* out        = d_out;

    int N = in_sizes[0] / FIN;   // 10000
    int E = in_sizes[1] / 2;     // 640000

    // workspace layout
    unsigned short* projb = (unsigned short*)d_ws;            // N*128 bf16
    unsigned short* skipb = projb + (size_t)N * FIN;          // N*128 bf16
    float* s_src    = (float*)(skipb + (size_t)N * FIN);      // N*8
    float* s_tgt    = s_src + (size_t)N * NH;                 // N*8
    int* sorted_src = (int*)(s_tgt + (size_t)N * NH);         // E
    int* offs       = sorted_src + E;                         // N+1
    int* tmp_off    = offs + (N + 1);                         // N
    int* bt         = tmp_off + N;                            // 64
    int* cnt        = bt + 64;                                // N (fallback)
    int* hist2d     = cnt + N;                                // HB*N
    int* pbase      = hist2d + (size_t)HB * N;                // HB*N

    int halfTiles  = (N + 15) / 16;        // 625
    int tiles      = 2 * halfTiles;        // 1250
    int perB       = (E + HB - 1) / HB;    // 5000

    void* args[] = { (void*)&x, (void*)&Wp, (void*)&Ws, (void*)&ssw, (void*)&stw,
                     (void*)&bias, (void*)&edges, (void*)&out,
                     (void*)&projb, (void*)&skipb, (void*)&s_src, (void*)&s_tgt,
                     (void*)&sorted_src, (void*)&offs, (void*)&tmp_off, (void*)&bt,
                     (void*)&hist2d, (void*)&pbase,
                     (void*)&N, (void*)&E, (void*)&perB, (void*)&tiles, (void*)&halfTiles };

    hipError_t err = hipLaunchCooperativeKernel(
        (const void*)k_gat, dim3(GRID), dim3(TPB), args, 0, stream);

    if (err != hipSuccess) {
        // Fallback: proven 5-kernel pipeline (R7). Deterministic path choice,
        // identical work every call.
        const int projBlocks = (tiles + 3) / 4;      // 313
        k_projhist<<<projBlocks + HB, 256, 0, stream>>>(
            x, Wp, Ws, ssw, stw, projb, skipb, s_src, s_tgt,
            edges, hist2d, N, E, tiles, halfTiles, projBlocks, perB);
        k_colscan<<<(N + 255) / 256, 256, 0, stream>>>(hist2d, pbase, cnt, N);
        k_offscan<<<1, 256, 0, stream>>>(cnt, offs, N);
        k_place<<<HB, 256, 0, stream>>>(edges, offs, pbase, sorted_src, N, E, perB);
        k_aggregate<<<N, 64, 0, stream>>>(offs, sorted_src, s_src, s_tgt, projb,
                                          skipb, bias, out, (const unsigned*)x);
    }
}

// Round 10
// 165.898 us; speedup vs baseline: 3.6094x; 3.6094x over previous
//
#include <hip/hip_runtime.h>
#include <hip/hip_bf16.h>

#define FIN   128
#define NH    8
#define NEG   0.2f
#define HB    128         // histogram/placement blocks
#define NMAX  10240       // LDS cursor capacity (40 KB in k_place)

typedef __attribute__((ext_vector_type(8))) short short8;   // 8 bf16 in 4 VGPRs
typedef __attribute__((ext_vector_type(4))) float f32x4;

// ---- helpers ----
__device__ __forceinline__ short f2bf(float f) {            // fp32 -> bf16 bits, RNE
    unsigned u = __float_as_uint(f);
    return (short)((u + 0x7FFFu + ((u >> 16) & 1u)) >> 16);
}
__device__ __forceinline__ float bflo(unsigned p) { return __uint_as_float(p << 16); }
__device__ __forceinline__ float bfhi(unsigned p) { return __uint_as_float(p & 0xFFFF0000u); }
__device__ __forceinline__ float ld_f(const void* p, int i, bool bf16) {
    if (bf16) {
        unsigned h = ((const unsigned short*)p)[i];
        return __uint_as_float(h << 16);
    }
    return ((const float*)p)[i];
}
__device__ __forceinline__ short8 ld_frag(const void* p, size_t off, bool bf16) {
    if (bf16) return *(const short8*)((const short*)p + off);
    const float* f = (const float*)p + off;
    f32x4 f0 = *(const f32x4*)f;
    f32x4 f1 = *(const f32x4*)(f + 4);
    short8 r;
    r[0] = f2bf(f0[0]); r[1] = f2bf(f0[1]); r[2] = f2bf(f0[2]); r[3] = f2bf(f0[3]);
    r[4] = f2bf(f1[0]); r[5] = f2bf(f1[1]); r[6] = f2bf(f1[2]); r[7] = f2bf(f1[3]);
    return r;
}
__device__ __forceinline__ float escore(float ss, float st) {
    float v = ss + st;
    v = v > 0.f ? v : NEG * v;                // leaky relu
    return __expf(fminf(v, 60.f));            // shift-free softmax numerator
}
// Per-wave dtype probes. All 64 lanes of the calling wave must be active.
__device__ __forceinline__ bool wave_bf16(const unsigned* x32) {
    unsigned w  = x32[threadIdx.x & 63];
    unsigned ex = (w >> 7) & 0xFFu;           // bf16 exponent of x[2*lane] if packed
    return __popcll(__ballot(ex >= 118u && ex <= 130u)) >= 48;
}
__device__ __forceinline__ bool wave_e64(const int* e32) {
    return __popcll(__ballot(e32[2 * (threadIdx.x & 63) + 1] == 0)) == 64;
}

// Kernel 1 (fused): blocks [0,projBlocks) = the two GEMMs (proj->bf16 + fused
// head scores; skip->bf16). Blocks [projBlocks, projBlocks+HB) = per-block
// 16-bit packed LDS histogram of tgt (per-block count <= perB=5000 < 2^16),
// written non-atomically to hist2d[b][*].
__global__ __launch_bounds__(256) void k_projhist(
    const void* __restrict__ x, const void* __restrict__ Wp,
    const void* __restrict__ Ws,
    const void* __restrict__ ssrcw, const void* __restrict__ stgtw,
    unsigned short* __restrict__ projb, unsigned short* __restrict__ skipb,
    float* __restrict__ s_src, float* __restrict__ s_tgt,
    const int* __restrict__ e32, int* __restrict__ hist2d,
    int N, int E, int tiles, int halfTiles, int projBlocks, int perB)
{
    __shared__ unsigned l32[NMAX / 2];        // 20 KB: two 16-bit bins per word
    if ((int)blockIdx.x >= projBlocks) {
        // ---- LDS histogram role (no global atomics) ----
        const bool e64 = wave_e64(e32);
        const int hb = (int)blockIdx.x - projBlocks;
        const int t = threadIdx.x;
        const int nw = (N + 1) >> 1;
        for (int j = t; j < nw; j += 256) l32[j] = 0;
        __syncthreads();
        const int lo = hb * perB;
        const int hi = min(lo + perB, E);
        for (int i = lo + t; i < hi; i += 256) {
            int tg = e64 ? e32[2 * ((size_t)E + i)] : e32[(size_t)E + i];
            atomicAdd(&l32[tg >> 1], 1u << ((tg & 1) << 4));   // LDS atomic
        }
        __syncthreads();
        for (int j = t; j < N; j += 256)
            hist2d[(size_t)hb * N + j] = (l32[j >> 1] >> ((j & 1) << 4)) & 0xFFFFu;
        return;
    }
    // ---- GEMM role ----
    const bool bf16 = wave_bf16((const unsigned*)x);
    const int lane = threadIdx.x & 63;
    const int wt = blockIdx.x * 4 + (threadIdx.x >> 6);
    if (wt >= tiles) return;
    const int mat = (wt >= halfTiles) ? 1 : 0;
    const int m0 = (mat ? wt - halfTiles : wt) * 16;
    const int mr = lane & 15;
    const int kb = lane >> 4;

    short8 a[4];
    const size_t xoff = (size_t)(m0 + mr) * FIN + kb * 8;
#pragma unroll
    for (int s = 0; s < 4; ++s) a[s] = ld_frag(x, xoff + s * 32, bf16);

    const void* W = mat ? Ws : Wp;
    f32x4 acc[8];
#pragma unroll
    for (int c = 0; c < 8; ++c) {
        acc[c] = (f32x4){0.f, 0.f, 0.f, 0.f};
        const size_t woff = (size_t)(c * 16 + mr) * FIN + kb * 8;
#pragma unroll
        for (int s = 0; s < 4; ++s) {
            short8 b = ld_frag(W, woff + s * 32, bf16);
            acc[c] = __builtin_amdgcn_mfma_f32_16x16x32_bf16(a[s], b, acc[c], 0, 0, 0);
        }
    }
    // D layout: col = lane&15, row = (lane>>4)*4 + r   [verified m89]
    if (mat == 0) {
#pragma unroll
        for (int c = 0; c < 8; ++c) {
            float sw = ld_f(ssrcw, c * 16 + mr, bf16);
            float tw = ld_f(stgtw, c * 16 + mr, bf16);
#pragma unroll
            for (int r = 0; r < 4; ++r) {
                int row = m0 + kb * 4 + r;
                float v = acc[c][r];
                projb[(size_t)row * FIN + c * 16 + mr] = (unsigned short)f2bf(v);
                float vs = v * sw, vt = v * tw;
#pragma unroll
                for (int o = 8; o >= 1; o >>= 1) {
                    vs += __shfl_xor(vs, o);
                    vt += __shfl_xor(vt, o);
                }
                if (mr == 0) {
                    s_src[row * NH + c] = vs;
                    s_tgt[row * NH + c] = vt;
                }
            }
        }
    } else {
#pragma unroll
        for (int c = 0; c < 8; ++c)
#pragma unroll
            for (int r = 0; r < 4; ++r)
                skipb[(size_t)(m0 + kb * 4 + r) * FIN + c * 16 + mr] =
                    (unsigned short)f2bf(acc[c][r]);
    }
}

// Kernel 2: per-bin exclusive prefix across the HB block-rows (coalesced:
// thread <-> bin). pbase[b][j] = sum_{b'<b} hist2d[b'][j]; cnt[j] = total.
__global__ __launch_bounds__(256) void k_colscan(
    const int* __restrict__ hist2d, int* __restrict__ pbase,
    int* __restrict__ cnt, int N)
{
    int j = blockIdx.x * 256 + threadIdx.x;
    if (j >= N) return;
    int s = 0;
#pragma unroll 4
    for (int b = 0; b < HB; ++b) {
        int v = hist2d[(size_t)b * N + j];
        pbase[(size_t)b * N + j] = s;
        s += v;
    }
    cnt[j] = s;
}

// Kernel 3: placement, with the offs-scan REDUNDANTLY recomputed per block
// (each block reads the same L2-resident cnt[] and runs the identical
// deterministic scan — zero inter-block communication, no fences, no
// election). Block 0 also publishes offs for k_aggregate (next dispatch —
// kernel boundary is the barrier). Then: LDS cursors; rank via LDS atomicAdd;
// one scattered 4B store per edge.
__global__ __launch_bounds__(256) void k_place(
    const int* __restrict__ e32, const int* __restrict__ cnt,
    const int* __restrict__ pbase, int* __restrict__ offs,
    int* __restrict__ sorted_src, int N, int E, int perB)
{
    __shared__ int cur[NMAX];
    __shared__ int sd[256];
    const bool e64 = wave_e64(e32);
    const int b = blockIdx.x, t = threadIdx.x;

    // ---- redundant exclusive scan of cnt -> thread-local offs chunk ----
    const int PER = (N + 255) / 256;          // 40 for N=10000
    const int base = t * PER;
    int local[40];                            // exclusive prefix within thread
    int sum = 0;
    for (int i = 0; i < PER && i < 40; ++i) {
        int idx = base + i;
        int v = (idx < N) ? cnt[idx] : 0;
        local[i] = sum;
        sum += v;
    }
    sd[t] = sum;
    __syncthreads();
#pragma unroll
    for (int off = 1; off < 256; off <<= 1) {
        int add = (t >= off) ? sd[t - off] : 0;
        __syncthreads();
        sd[t] += add;
        __syncthreads();
    }
    const int excl = sd[t] - sum;             // exclusive across threads
    // seed LDS cursors (thread t owns bins [base, base+PER)) and, from block
    // 0 only, publish offs for the next dispatch.
    for (int i = 0; i < PER && i < 40; ++i) {
        int idx = base + i;
        if (idx < N) {
            int o = excl + local[i];
            cur[idx] = o + pbase[(size_t)b * N + idx];
            if (b == 0) offs[idx] = o;
        }
    }
    if (b == 0 && t == 255) offs[N] = sd[255];
    __syncthreads();

    // ---- placement ----
    const int lo = b * perB;
    const int hi = min(lo + perB, E);
    for (int i = lo + t; i < hi; i += 256) {
        int s, tg;
        if (e64) { s = e32[2 * (size_t)i]; tg = e32[2 * ((size_t)E + i)]; }
        else     { s = e32[i];             tg = e32[(size_t)E + i]; }
        int pos = atomicAdd(&cur[tg], 1);  // LDS atomic
        sorted_src[pos] = s;
    }
}

// Kernel 4: one WAVE per node. Lane l owns column pair (2l, 2l+1) — both in
// head l>>3 — gathered as ONE packed bf16x2 4B load per edge. Numerator and
// denominator accumulate in registers; skip+bias epilogue. 4 independent
// gather chains + next-group index prefetch (overlaps sorted_src latency
// with the gathers/FMAs of the current group).
__global__ __launch_bounds__(64) void k_aggregate(
    const int* __restrict__ offs, const int* __restrict__ sorted_src,
    const float* __restrict__ s_src, const float* __restrict__ s_tgt,
    const unsigned short* __restrict__ projb, const unsigned short* __restrict__ skipb,
    const void* __restrict__ bias, void* __restrict__ out,
    const unsigned* __restrict__ x32)
{
    const bool bf16 = wave_bf16(x32);
    const int n = blockIdx.x, l = threadIdx.x;
    const int start = offs[n], end = offs[n + 1];
    const int h = l >> 3;
    const int c2 = l * 2;
    const float st = s_tgt[(size_t)n * NH + h];

    float ae0 = 0.f, ao0 = 0.f, ae1 = 0.f, ao1 = 0.f;
    float ae2 = 0.f, ao2 = 0.f, ae3 = 0.f, ao3 = 0.f;
    float d0 = 0.f, d1 = 0.f, d2 = 0.f, d3 = 0.f;

    const int cnt4 = (end - start) >> 2;
    int e = start;
    if (cnt4 > 0) {
        int s0 = sorted_src[e],     s1 = sorted_src[e + 1];
        int s2 = sorted_src[e + 2], s3 = sorted_src[e + 3];
        for (int g = 0; g < cnt4; ++g) {
            const int t0 = s0, t1 = s1, t2 = s2, t3 = s3;
            e += 4;
            if (g + 1 < cnt4) {               // wave-uniform prefetch
                s0 = sorted_src[e];     s1 = sorted_src[e + 1];
                s2 = sorted_src[e + 2]; s3 = sorted_src[e + 3];
            }
            float w0 = escore(s_src[(size_t)t0 * NH + h], st);
            float w1 = escore(s_src[(size_t)t1 * NH + h], st);
            float w2 = escore(s_src[(size_t)t2 * NH + h], st);
            float w3 = escore(s_src[(size_t)t3 * NH + h], st);
            unsigned p0 = *(const unsigned*)(projb + (size_t)t0 * FIN + c2);
            unsigned p1 = *(const unsigned*)(projb + (size_t)t1 * FIN + c2);
            unsigned p2 = *(const unsigned*)(projb + (size_t)t2 * FIN + c2);
            unsigned p3 = *(const unsigned*)(projb + (size_t)t3 * FIN + c2);
            ae0 += w0 * bflo(p0); ao0 += w0 * bfhi(p0); d0 += w0;
            ae1 += w1 * bflo(p1); ao1 += w1 * bfhi(p1); d1 += w1;
            ae2 += w2 * bflo(p2); ao2 += w2 * bfhi(p2); d2 += w2;
            ae3 += w3 * bflo(p3); ao3 += w3 * bfhi(p3); d3 += w3;
        }
    }
    for (; e < end; ++e) {
        int s = sorted_src[e];
        float w = escore(s_src[(size_t)s * NH + h], st);
        unsigned p = *(const unsigned*)(projb + (size_t)s * FIN + c2);
        ae0 += w * bflo(p); ao0 += w * bfhi(p); d0 += w;
    }

    float inv = 1.f / (((d0 + d1) + (d2 + d3)) + 1e-16f);
    unsigned skp = *(const unsigned*)(skipb + (size_t)n * FIN + c2);
    float be, bo;
    if (bf16) {
        unsigned bb = *(const unsigned*)((const unsigned short*)bias + c2);
        be = bflo(bb); bo = bfhi(bb);
    } else {
        float2 b2 = *(const float2*)((const float*)bias + c2);
        be = b2.x; bo = b2.y;
    }
    float oe = ((ae0 + ae1) + (ae2 + ae3)) * inv + bflo(skp) + be;
    float oo = ((ao0 + ao1) + (ao2 + ao3)) * inv + bfhi(skp) + bo;
    if (bf16) {
        unsigned pr = ((unsigned)(unsigned short)f2bf(oo) << 16)
                    | (unsigned)(unsigned short)f2bf(oe);
        ((unsigned*)out)[((size_t)n * FIN + c2) >> 1] = pr;
    } else {
        float2 o2; o2.x = oe; o2.y = oo;
        *(float2*)((float*)out + (size_t)n * FIN + c2) = o2;
    }
}

extern "C" void kernel_launch(void* const* d_in, const int* in_sizes, int n_in,
                              void* d_out, int out_size, void* d_ws, size_t ws_size,
                              hipStream_t stream)
{
    const void* x    = d_in[0];
    const int* edges = (const int*)d_in[1];
    const void* Wp   = d_in[2];
    const void* Ws   = d_in[3];
    const void* ssw  = d_in[4];
    const void* stw  = d_in[5];
    const void* bias = d_in[6];

    const int N = in_sizes[0] / FIN;   // 10000
    const int E = in_sizes[1] / 2;     // 640000

    // workspace layout
    unsigned short* projb = (unsigned short*)d_ws;            // N*128 bf16
    unsigned short* skipb = projb + (size_t)N * FIN;          // N*128 bf16
    float* s_src    = (float*)(skipb + (size_t)N * FIN);      // N*8
    float* s_tgt    = s_src + (size_t)N * NH;                 // N*8
    int* sorted_src = (int*)(s_tgt + (size_t)N * NH);         // E
    int* offs       = sorted_src + E;                         // N+1
    int* cnt        = offs + (N + 1);                         // N
    int* hist2d     = cnt + N;                                // HB*N
    int* pbase      = hist2d + (size_t)HB * N;                // HB*N

    const int halfTiles  = (N + 15) / 16;        // 625
    const int tiles      = 2 * halfTiles;        // 1250
    const int projBlocks = (tiles + 3) / 4;      // 313
    const int perB       = (E + HB - 1) / HB;    // 5000

    k_projhist<<<projBlocks + HB, 256, 0, stream>>>(
        x, Wp, Ws, ssw, stw, projb, skipb, s_src, s_tgt,
        edges, hist2d, N, E, tiles, halfTiles, projBlocks, perB);
    k_colscan<<<(N + 255) / 256, 256, 0, stream>>>(hist2d, pbase, cnt, N);
    k_place<<<HB, 256, 0, stream>>>(edges, cnt, pbase, offs, sorted_src, N, E, perB);
    k_aggregate<<<N, 64, 0, stream>>>(offs, sorted_src, s_src, s_tgt, projb,
                                      skipb, bias, d_out, (const unsigned*)x);
}

// Round 11
// 148.038 us; speedup vs baseline: 4.0449x; 1.1206x over previous
//
#include <hip/hip_runtime.h>
#include <hip/hip_bf16.h>

#define FIN   128
#define NH    8
#define NEG   0.2f
#define HB    256         // histogram/placement blocks (1 per CU)
#define NMAX  10240       // LDS cursor capacity (40 KB in k_place)

typedef __attribute__((ext_vector_type(8))) short short8;   // 8 bf16 in 4 VGPRs
typedef __attribute__((ext_vector_type(4))) float f32x4;

// ---- helpers ----
__device__ __forceinline__ short f2bf(float f) {            // fp32 -> bf16 bits, RNE
    unsigned u = __float_as_uint(f);
    return (short)((u + 0x7FFFu + ((u >> 16) & 1u)) >> 16);
}
__device__ __forceinline__ float bflo(unsigned p) { return __uint_as_float(p << 16); }
__device__ __forceinline__ float bfhi(unsigned p) { return __uint_as_float(p & 0xFFFF0000u); }
__device__ __forceinline__ float ld_f(const void* p, int i, bool bf16) {
    if (bf16) {
        unsigned h = ((const unsigned short*)p)[i];
        return __uint_as_float(h << 16);
    }
    return ((const float*)p)[i];
}
__device__ __forceinline__ short8 ld_frag(const void* p, size_t off, bool bf16) {
    if (bf16) return *(const short8*)((const short*)p + off);
    const float* f = (const float*)p + off;
    f32x4 f0 = *(const f32x4*)f;
    f32x4 f1 = *(const f32x4*)(f + 4);
    short8 r;
    r[0] = f2bf(f0[0]); r[1] = f2bf(f0[1]); r[2] = f2bf(f0[2]); r[3] = f2bf(f0[3]);
    r[4] = f2bf(f1[0]); r[5] = f2bf(f1[1]); r[6] = f2bf(f1[2]); r[7] = f2bf(f1[3]);
    return r;
}
__device__ __forceinline__ float escore(float ss, float st) {
    float v = ss + st;
    v = v > 0.f ? v : NEG * v;                // leaky relu
    return __expf(fminf(v, 60.f));            // shift-free softmax numerator
}
// Per-wave dtype probes. All 64 lanes of the calling wave must be active.
__device__ __forceinline__ bool wave_bf16(const unsigned* x32) {
    unsigned w  = x32[threadIdx.x & 63];
    unsigned ex = (w >> 7) & 0xFFu;           // bf16 exponent of x[2*lane] if packed
    return __popcll(__ballot(ex >= 118u && ex <= 130u)) >= 48;
}
__device__ __forceinline__ bool wave_e64(const int* e32) {
    return __popcll(__ballot(e32[2 * (threadIdx.x & 63) + 1] == 0)) == 64;
}

// Kernel 1 (fused): blocks [0,projBlocks) = the two GEMMs (proj->bf16 + fused
// head scores; skip->bf16). Blocks [projBlocks, projBlocks+HB) = per-block
// 16-bit packed LDS histogram of tgt (per-block count <= perB=2500 < 2^16),
// written non-atomically to hist2d[b][*].
__global__ __launch_bounds__(256) void k_projhist(
    const void* __restrict__ x, const void* __restrict__ Wp,
    const void* __restrict__ Ws,
    const void* __restrict__ ssrcw, const void* __restrict__ stgtw,
    unsigned short* __restrict__ projb, unsigned short* __restrict__ skipb,
    float* __restrict__ s_src, float* __restrict__ s_tgt,
    const int* __restrict__ e32, int* __restrict__ hist2d,
    int N, int E, int tiles, int halfTiles, int projBlocks, int perB)
{
    __shared__ unsigned l32[NMAX / 2];        // 20 KB: two 16-bit bins per word
    if ((int)blockIdx.x >= projBlocks) {
        // ---- LDS histogram role (no global atomics) ----
        const bool e64 = wave_e64(e32);
        const int hb = (int)blockIdx.x - projBlocks;
        const int t = threadIdx.x;
        const int nw = (N + 1) >> 1;
        for (int j = t; j < nw; j += 256) l32[j] = 0;
        __syncthreads();
        const int lo = hb * perB;
        const int hi = min(lo + perB, E);
        for (int i = lo + t; i < hi; i += 256) {
            int tg = e64 ? e32[2 * ((size_t)E + i)] : e32[(size_t)E + i];
            atomicAdd(&l32[tg >> 1], 1u << ((tg & 1) << 4));   // LDS atomic
        }
        __syncthreads();
        for (int j = t; j < N; j += 256)
            hist2d[(size_t)hb * N + j] = (l32[j >> 1] >> ((j & 1) << 4)) & 0xFFFFu;
        return;
    }
    // ---- GEMM role ----
    const bool bf16 = wave_bf16((const unsigned*)x);
    const int lane = threadIdx.x & 63;
    const int wt = blockIdx.x * 4 + (threadIdx.x >> 6);
    if (wt >= tiles) return;
    const int mat = (wt >= halfTiles) ? 1 : 0;
    const int m0 = (mat ? wt - halfTiles : wt) * 16;
    const int mr = lane & 15;
    const int kb = lane >> 4;

    short8 a[4];
    const size_t xoff = (size_t)(m0 + mr) * FIN + kb * 8;
#pragma unroll
    for (int s = 0; s < 4; ++s) a[s] = ld_frag(x, xoff + s * 32, bf16);

    const void* W = mat ? Ws : Wp;
    f32x4 acc[8];
#pragma unroll
    for (int c = 0; c < 8; ++c) {
        acc[c] = (f32x4){0.f, 0.f, 0.f, 0.f};
        const size_t woff = (size_t)(c * 16 + mr) * FIN + kb * 8;
#pragma unroll
        for (int s = 0; s < 4; ++s) {
            short8 b = ld_frag(W, woff + s * 32, bf16);
            acc[c] = __builtin_amdgcn_mfma_f32_16x16x32_bf16(a[s], b, acc[c], 0, 0, 0);
        }
    }
    // D layout: col = lane&15, row = (lane>>4)*4 + r   [verified m89]
    if (mat == 0) {
#pragma unroll
        for (int c = 0; c < 8; ++c) {
            float sw = ld_f(ssrcw, c * 16 + mr, bf16);
            float tw = ld_f(stgtw, c * 16 + mr, bf16);
#pragma unroll
            for (int r = 0; r < 4; ++r) {
                int row = m0 + kb * 4 + r;
                float v = acc[c][r];
                projb[(size_t)row * FIN + c * 16 + mr] = (unsigned short)f2bf(v);
                float vs = v * sw, vt = v * tw;
#pragma unroll
                for (int o = 8; o >= 1; o >>= 1) {
                    vs += __shfl_xor(vs, o);
                    vt += __shfl_xor(vt, o);
                }
                if (mr == 0) {
                    s_src[row * NH + c] = vs;
                    s_tgt[row * NH + c] = vt;
                }
            }
        }
    } else {
#pragma unroll
        for (int c = 0; c < 8; ++c)
#pragma unroll
            for (int r = 0; r < 4; ++r)
                skipb[(size_t)(m0 + kb * 4 + r) * FIN + c * 16 + mr] =
                    (unsigned short)f2bf(acc[c][r]);
    }
}

// Kernel 2: per-bin exclusive prefix across the HB block-rows (coalesced:
// thread <-> bin). pbase[b][j] = sum_{b'<b} hist2d[b'][j]; cnt[j] = total.
// Zeroes the cnt pad region [N, Npad) so k_place can int4-scan it.
__global__ __launch_bounds__(256) void k_colscan(
    const int* __restrict__ hist2d, int* __restrict__ pbase,
    int* __restrict__ cnt, int N, int Npad)
{
    int j = blockIdx.x * 256 + threadIdx.x;
    if (j >= N) { if (j < Npad) cnt[j] = 0; return; }
    int s = 0;
#pragma unroll 8
    for (int b = 0; b < HB; ++b) {
        int v = hist2d[(size_t)b * N + j];
        pbase[(size_t)b * N + j] = s;
        s += v;
    }
    cnt[j] = s;
}

// Kernel 3: placement. Redundant per-block offs-scan (zero inter-block
// communication — kernel boundary is the barrier), fully vectorized:
// int4 loads of cnt/pbase, prefix reconstructed in registers, no scratch.
// Main loop: all (src,tgt) pairs preloaded into registers, then the LDS
// atomic rank + scattered 4B store sweep. Block 0 publishes offs.
__global__ __launch_bounds__(256) void k_place(
    const int* __restrict__ e32, const int* __restrict__ cnt,
    const int* __restrict__ pbase, int* __restrict__ offs,
    int* __restrict__ sorted_src, int N, int E, int perB)
{
    __shared__ int cur[NMAX];
    __shared__ int sd[256];
    const bool e64 = wave_e64(e32);
    const int b = blockIdx.x, t = threadIdx.x;
    const int PER = (N + 255) / 256;

    if (PER == 40 && (N & 3) == 0) {
        // ---- fast vectorized two-pass scan (N in (9984,10240], mult of 4) ----
        const int4* c4 = (const int4*)cnt + t * 10;
        int4 v[10];
        int sum = 0;
#pragma unroll
        for (int q = 0; q < 10; ++q) {
            v[q] = c4[q];                     // pad region is zeroed by colscan
            sum += (v[q].x + v[q].y) + (v[q].z + v[q].w);
        }
        sd[t] = sum;
        __syncthreads();
#pragma unroll
        for (int off = 1; off < 256; off <<= 1) {
            int add = (t >= off) ? sd[t - off] : 0;
            __syncthreads();
            sd[t] += add;
            __syncthreads();
        }
        int run = sd[t] - sum;                // exclusive prefix at this thread
        const int base = t * 40;
        const int4* pb4 = (const int4*)(pbase + (size_t)b * N) + t * 10;
#pragma unroll
        for (int q = 0; q < 10; ++q) {
            int4 pb = pb4[q];                 // +pad alloc covers tail reads
            int idx = base + q * 4;
            int r0 = run;
            int r1 = r0 + v[q].x;
            int r2 = r1 + v[q].y;
            int r3 = r2 + v[q].z;
            cur[idx]     = r0 + pb.x;         // idx may be in [N,NMAX) pad: harmless
            cur[idx + 1] = r1 + pb.y;
            cur[idx + 2] = r2 + pb.z;
            cur[idx + 3] = r3 + pb.w;
            if (b == 0) {
                if (idx     < N) offs[idx]     = r0;
                if (idx + 1 < N) offs[idx + 1] = r1;
                if (idx + 2 < N) offs[idx + 2] = r2;
                if (idx + 3 < N) offs[idx + 3] = r3;
            }
            run = r3 + v[q].w;
        }
        if (b == 0 && t == 255) offs[N] = run;
    } else {
        // ---- generic scalar fallback ----
        int sum = 0;
        for (int i = 0; i < PER; ++i) {
            int idx = t * PER + i;
            sum += (idx < N) ? cnt[idx] : 0;
        }
        sd[t] = sum;
        __syncthreads();
#pragma unroll
        for (int off = 1; off < 256; off <<= 1) {
            int add = (t >= off) ? sd[t - off] : 0;
            __syncthreads();
            sd[t] += add;
            __syncthreads();
        }
        int run = sd[t] - sum;
        for (int i = 0; i < PER; ++i) {
            int idx = t * PER + i;
            if (idx < N) {
                cur[idx] = run + pbase[(size_t)b * N + idx];
                if (b == 0) offs[idx] = run;
                run += cnt[idx];
            }
        }
        if (b == 0 && t == 255) offs[N] = run;
    }
    __syncthreads();

    // ---- placement: preload all edge pairs, then atomic+store sweep ----
    const int lo = b * perB;
    const int hi = min(lo + perB, E);
    int se[10], te[10];
#pragma unroll
    for (int k = 0; k < 10; ++k) {
        int i = lo + t + k * 256;
        te[k] = -1;
        if (i < hi) {
            if (e64) { se[k] = e32[2 * (size_t)i]; te[k] = e32[2 * ((size_t)E + i)]; }
            else     { se[k] = e32[i];             te[k] = e32[(size_t)E + i]; }
        }
    }
#pragma unroll
    for (int k = 0; k < 10; ++k) {
        if (te[k] >= 0) {
            int pos = atomicAdd(&cur[te[k]], 1);   // LDS atomic
            sorted_src[pos] = se[k];
        }
    }
    // tail for perB > 2560 (not hit at E=640k, HB=256)
    for (int i = lo + t + 10 * 256; i < hi; i += 256) {
        int s, tg;
        if (e64) { s = e32[2 * (size_t)i]; tg = e32[2 * ((size_t)E + i)]; }
        else     { s = e32[i];             tg = e32[(size_t)E + i]; }
        int pos = atomicAdd(&cur[tg], 1);
        sorted_src[pos] = s;
    }
}

// Kernel 4: one WAVE per node. Lane l owns column pair (2l, 2l+1) — both in
// head l>>3 — gathered as ONE packed bf16x2 4B load per edge. Numerator and
// denominator accumulate in registers; skip+bias epilogue. 4 independent
// gather chains + next-group index prefetch.
__global__ __launch_bounds__(64) void k_aggregate(
    const int* __restrict__ offs, const int* __restrict__ sorted_src,
    const float* __restrict__ s_src, const float* __restrict__ s_tgt,
    const unsigned short* __restrict__ projb, const unsigned short* __restrict__ skipb,
    const void* __restrict__ bias, void* __restrict__ out,
    const unsigned* __restrict__ x32)
{
    const bool bf16 = wave_bf16(x32);
    const int n = blockIdx.x, l = threadIdx.x;
    const int start = offs[n], end = offs[n + 1];
    const int h = l >> 3;
    const int c2 = l * 2;
    const float st = s_tgt[(size_t)n * NH + h];

    float ae0 = 0.f, ao0 = 0.f, ae1 = 0.f, ao1 = 0.f;
    float ae2 = 0.f, ao2 = 0.f, ae3 = 0.f, ao3 = 0.f;
    float d0 = 0.f, d1 = 0.f, d2 = 0.f, d3 = 0.f;

    const int cnt4 = (end - start) >> 2;
    int e = start;
    if (cnt4 > 0) {
        int s0 = sorted_src[e],     s1 = sorted_src[e + 1];
        int s2 = sorted_src[e + 2], s3 = sorted_src[e + 3];
        for (int g = 0; g < cnt4; ++g) {
            const int t0 = s0, t1 = s1, t2 = s2, t3 = s3;
            e += 4;
            if (g + 1 < cnt4) {               // wave-uniform prefetch
                s0 = sorted_src[e];     s1 = sorted_src[e + 1];
                s2 = sorted_src[e + 2]; s3 = sorted_src[e + 3];
            }
            float w0 = escore(s_src[(size_t)t0 * NH + h], st);
            float w1 = escore(s_src[(size_t)t1 * NH + h], st);
            float w2 = escore(s_src[(size_t)t2 * NH + h], st);
            float w3 = escore(s_src[(size_t)t3 * NH + h], st);
            unsigned p0 = *(const unsigned*)(projb + (size_t)t0 * FIN + c2);
            unsigned p1 = *(const unsigned*)(projb + (size_t)t1 * FIN + c2);
            unsigned p2 = *(const unsigned*)(projb + (size_t)t2 * FIN + c2);
            unsigned p3 = *(const unsigned*)(projb + (size_t)t3 * FIN + c2);
            ae0 += w0 * bflo(p0); ao0 += w0 * bfhi(p0); d0 += w0;
            ae1 += w1 * bflo(p1); ao1 += w1 * bfhi(p1); d1 += w1;
            ae2 += w2 * bflo(p2); ao2 += w2 * bfhi(p2); d2 += w2;
            ae3 += w3 * bflo(p3); ao3 += w3 * bfhi(p3); d3 += w3;
        }
    }
    for (; e < end; ++e) {
        int s = sorted_src[e];
        float w = escore(s_src[(size_t)s * NH + h], st);
        unsigned p = *(const unsigned*)(projb + (size_t)s * FIN + c2);
        ae0 += w * bflo(p); ao0 += w * bfhi(p); d0 += w;
    }

    float inv = 1.f / (((d0 + d1) + (d2 + d3)) + 1e-16f);
    unsigned skp = *(const unsigned*)(skipb + (size_t)n * FIN + c2);
    float be, bo;
    if (bf16) {
        unsigned bb = *(const unsigned*)((const unsigned short*)bias + c2);
        be = bflo(bb); bo = bfhi(bb);
    } else {
        float2 b2 = *(const float2*)((const float*)bias + c2);
        be = b2.x; bo = b2.y;
    }
    float oe = ((ae0 + ae1) + (ae2 + ae3)) * inv + bflo(skp) + be;
    float oo = ((ao0 + ao1) + (ao2 + ao3)) * inv + bfhi(skp) + bo;
    if (bf16) {
        unsigned pr = ((unsigned)(unsigned short)f2bf(oo) << 16)
                    | (unsigned)(unsigned short)f2bf(oe);
        ((unsigned*)out)[((size_t)n * FIN + c2) >> 1] = pr;
    } else {
        float2 o2; o2.x = oe; o2.y = oo;
        *(float2*)((float*)out + (size_t)n * FIN + c2) = o2;
    }
}

extern "C" void kernel_launch(void* const* d_in, const int* in_sizes, int n_in,
                              void* d_out, int out_size, void* d_ws, size_t ws_size,
                              hipStream_t stream)
{
    const void* x    = d_in[0];
    const int* edges = (const int*)d_in[1];
    const void* Wp   = d_in[2];
    const void* Ws   = d_in[3];
    const void* ssw  = d_in[4];
    const void* stw  = d_in[5];
    const void* bias = d_in[6];

    const int N = in_sizes[0] / FIN;   // 10000
    const int E = in_sizes[1] / 2;     // 640000
    const int PER  = (N + 255) / 256;
    const int Npad = PER * 256;        // 10240

    // workspace layout (aligned: every array starts on a 256 B boundary)
    char* wp = (char*)d_ws;
    auto takeB = [&wp](size_t bytes) {
        char* p = wp;
        wp += (bytes + 255) & ~(size_t)255;
        return p;
    };
    unsigned short* projb = (unsigned short*)takeB((size_t)N * FIN * 2);
    unsigned short* skipb = (unsigned short*)takeB((size_t)N * FIN * 2);
    float* s_src    = (float*)takeB((size_t)N * NH * 4);
    float* s_tgt    = (float*)takeB((size_t)N * NH * 4);
    int* sorted_src = (int*)takeB((size_t)E * 4);
    int* offs       = (int*)takeB((size_t)(N + 8) * 4);
    int* cnt        = (int*)takeB((size_t)Npad * 4);
    int* hist2d     = (int*)takeB((size_t)HB * N * 4);
    int* pbase      = (int*)takeB((size_t)HB * N * 4 + 4096);  // +pad for int4 tail

    const int halfTiles  = (N + 15) / 16;        // 625
    const int tiles      = 2 * halfTiles;        // 1250
    const int projBlocks = (tiles + 3) / 4;      // 313
    const int perB       = (E + HB - 1) / HB;    // 2500

    k_projhist<<<projBlocks + HB, 256, 0, stream>>>(
        x, Wp, Ws, ssw, stw, projb, skipb, s_src, s_tgt,
        edges, hist2d, N, E, tiles, halfTiles, projBlocks, perB);
    k_colscan<<<Npad / 256, 256, 0, stream>>>(hist2d, pbase, cnt, N, Npad);
    k_place<<<HB, 256, 0, stream>>>(edges, cnt, pbase, offs, sorted_src, N, E, perB);
    k_aggregate<<<N, 64, 0, stream>>>(offs, sorted_src, s_src, s_tgt, projb,
                                      skipb, bias, d_out, (const unsigned*)x);
}

// Round 12
// 135.935 us; speedup vs baseline: 4.4050x; 1.0890x over previous
//
#include <hip/hip_runtime.h>
#include <hip/hip_bf16.h>

#define FIN   128
#define NH    8
#define NEG   0.2f
#define HB    256         // histogram/placement blocks (1 per CU)
#define NMAX  10240       // LDS cursor capacity / padded bin count
#define RSW   (NMAX / 2)  // packed row stride in uint words (5120)

typedef __attribute__((ext_vector_type(8))) short short8;   // 8 bf16 in 4 VGPRs
typedef __attribute__((ext_vector_type(4))) float f32x4;

// ---- helpers ----
__device__ __forceinline__ short f2bf(float f) {            // fp32 -> bf16 bits, RNE
    unsigned u = __float_as_uint(f);
    return (short)((u + 0x7FFFu + ((u >> 16) & 1u)) >> 16);
}
__device__ __forceinline__ float bflo(unsigned p) { return __uint_as_float(p << 16); }
__device__ __forceinline__ float bfhi(unsigned p) { return __uint_as_float(p & 0xFFFF0000u); }
__device__ __forceinline__ float ld_f(const void* p, int i, bool bf16) {
    if (bf16) {
        unsigned h = ((const unsigned short*)p)[i];
        return __uint_as_float(h << 16);
    }
    return ((const float*)p)[i];
}
__device__ __forceinline__ short8 ld_frag(const void* p, size_t off, bool bf16) {
    if (bf16) return *(const short8*)((const short*)p + off);
    const float* f = (const float*)p + off;
    f32x4 f0 = *(const f32x4*)f;
    f32x4 f1 = *(const f32x4*)(f + 4);
    short8 r;
    r[0] = f2bf(f0[0]); r[1] = f2bf(f0[1]); r[2] = f2bf(f0[2]); r[3] = f2bf(f0[3]);
    r[4] = f2bf(f1[0]); r[5] = f2bf(f1[1]); r[6] = f2bf(f1[2]); r[7] = f2bf(f1[3]);
    return r;
}
__device__ __forceinline__ float escore(float ss, float st) {
    float v = ss + st;
    v = v > 0.f ? v : NEG * v;                // leaky relu
    return __expf(fminf(v, 60.f));            // shift-free softmax numerator
}
// Per-wave dtype probes. All 64 lanes of the calling wave must be active.
__device__ __forceinline__ bool wave_bf16(const unsigned* x32) {
    unsigned w  = x32[threadIdx.x & 63];
    unsigned ex = (w >> 7) & 0xFFu;           // bf16 exponent of x[2*lane] if packed
    return __popcll(__ballot(ex >= 118u && ex <= 130u)) >= 48;
}
__device__ __forceinline__ bool wave_e64(const int* e32) {
    return __popcll(__ballot(e32[2 * (threadIdx.x & 63) + 1] == 0)) == 64;
}

// Kernel 1: per-block 16-bit packed LDS histogram of tgt (per-block count
// <= perB=2500 < 2^16). Writeback is the RAW packed words — no unpack.
__global__ __launch_bounds__(256) void k_hist(
    const int* __restrict__ e32, unsigned* __restrict__ hist2w,
    int N, int E, int perB)
{
    __shared__ unsigned l32[RSW];             // 20 KB: two 16-bit bins per word
    const bool e64 = wave_e64(e32);
    const int b = blockIdx.x, t = threadIdx.x;
    const int nw = (N + 1) >> 1;
    for (int j = t; j < nw; j += 256) l32[j] = 0;
    __syncthreads();
    const int lo = b * perB;
    const int hi = min(lo + perB, E);
    for (int i = lo + t; i < hi; i += 256) {
        int tg = e64 ? ((const int2*)e32)[(size_t)E + i].x : e32[(size_t)E + i];
        atomicAdd(&l32[tg >> 1], 1u << ((tg & 1) << 4));   // LDS atomic
    }
    __syncthreads();
    // packed writeback, uint4-vectorized
    const int nw4 = (nw + 3) >> 2;            // 1250 for N=10000
    uint4* dst = (uint4*)(hist2w + (size_t)b * RSW);
    const uint4* src = (const uint4*)l32;
    for (int j = t; j < nw4; j += 256) dst[j] = src[j];
}

// Kernel 2 (fused): blocks [0, csBlocks) = packed column-scan (per-bin
// exclusive prefix across the HB hist rows; thread <-> bin-pair word,
// coalesced). Blocks [csBlocks, ...) = the two GEMMs (proj->bf16 + fused
// head scores; skip->bf16). Neither role uses LDS -> zero interference.
__global__ __launch_bounds__(256) void k_gemmscan(
    const void* __restrict__ x, const void* __restrict__ Wp,
    const void* __restrict__ Ws,
    const void* __restrict__ ssrcw, const void* __restrict__ stgtw,
    unsigned short* __restrict__ projb, unsigned short* __restrict__ skipb,
    float* __restrict__ s_src, float* __restrict__ s_tgt,
    const unsigned* __restrict__ hist2w, unsigned* __restrict__ pbase2w,
    unsigned* __restrict__ cnt2w,
    int N, int tiles, int halfTiles, int csBlocks)
{
    if ((int)blockIdx.x < csBlocks) {
        // ---- packed column scan ----
        const int j = blockIdx.x * 256 + threadIdx.x;   // word index (bin pair)
        if (j >= RSW) return;
        const int nw = (N + 1) >> 1;
        if (j >= nw) { cnt2w[j] = 0; return; }          // zero the pad words
        unsigned s0 = 0, s1 = 0;
#pragma unroll 8
        for (int r = 0; r < HB; ++r) {
            unsigned v = hist2w[(size_t)r * RSW + j];
            pbase2w[(size_t)r * RSW + j] = s0 | (s1 << 16);   // exclusive
            s0 += v & 0xFFFFu;
            s1 += v >> 16;
        }
        cnt2w[j] = s0 | (s1 << 16);
        return;
    }
    // ---- GEMM role ----
    const int wt = ((int)blockIdx.x - csBlocks) * 4 + ((int)threadIdx.x >> 6);
    if (wt >= tiles) return;
    const bool bf16 = wave_bf16((const unsigned*)x);
    const int lane = threadIdx.x & 63;
    const int mat = (wt >= halfTiles) ? 1 : 0;
    const int m0 = (mat ? wt - halfTiles : wt) * 16;
    const int mr = lane & 15;
    const int kb = lane >> 4;

    short8 a[4];
    const size_t xoff = (size_t)(m0 + mr) * FIN + kb * 8;
#pragma unroll
    for (int s = 0; s < 4; ++s) a[s] = ld_frag(x, xoff + s * 32, bf16);

    const void* W = mat ? Ws : Wp;
    f32x4 acc[8];
#pragma unroll
    for (int c = 0; c < 8; ++c) {
        acc[c] = (f32x4){0.f, 0.f, 0.f, 0.f};
        const size_t woff = (size_t)(c * 16 + mr) * FIN + kb * 8;
#pragma unroll
        for (int s = 0; s < 4; ++s) {
            short8 b = ld_frag(W, woff + s * 32, bf16);
            acc[c] = __builtin_amdgcn_mfma_f32_16x16x32_bf16(a[s], b, acc[c], 0, 0, 0);
        }
    }
    // D layout: col = lane&15, row = (lane>>4)*4 + r   [verified m89]
    if (mat == 0) {
#pragma unroll
        for (int c = 0; c < 8; ++c) {
            float sw = ld_f(ssrcw, c * 16 + mr, bf16);
            float tw = ld_f(stgtw, c * 16 + mr, bf16);
#pragma unroll
            for (int r = 0; r < 4; ++r) {
                int row = m0 + kb * 4 + r;
                float v = acc[c][r];
                projb[(size_t)row * FIN + c * 16 + mr] = (unsigned short)f2bf(v);
                float vs = v * sw, vt = v * tw;
#pragma unroll
                for (int o = 8; o >= 1; o >>= 1) {
                    vs += __shfl_xor(vs, o);
                    vt += __shfl_xor(vt, o);
                }
                if (mr == 0) {
                    s_src[row * NH + c] = vs;
                    s_tgt[row * NH + c] = vt;
                }
            }
        }
    } else {
#pragma unroll
        for (int c = 0; c < 8; ++c)
#pragma unroll
            for (int r = 0; r < 4; ++r)
                skipb[(size_t)(m0 + kb * 4 + r) * FIN + c * 16 + mr] =
                    (unsigned short)f2bf(acc[c][r]);
    }
}

// Kernel 3: placement. Redundant per-block offs-scan (zero inter-block
// communication — kernel boundary is the barrier) over the PACKED cnt/pbase:
// uint4 loads, prefix rebuilt in registers, no scratch arrays. Pad bins
// [N, NMAX) have cnt=0 (colscan) so garbage pbase there is never consumed.
// Main loop: all (src,tgt) preloaded, then LDS-atomic rank + 4B store sweep.
// Block 0 publishes offs for k_aggregate.
__global__ __launch_bounds__(256) void k_place(
    const int* __restrict__ e32, const unsigned* __restrict__ cnt2w,
    const unsigned* __restrict__ pbase2w, int* __restrict__ offs,
    int* __restrict__ sorted_src, int N, int E, int perB)
{
    __shared__ int cur[NMAX];
    __shared__ int sd[256];
    const bool e64 = wave_e64(e32);
    const int b = blockIdx.x, t = threadIdx.x;

    // ---- vectorized redundant scan: 20 packed words = 40 bins per thread ----
    {
        const uint4* c4 = (const uint4*)cnt2w + t * 5;
        uint4 v[5];
        int sum = 0;
#pragma unroll
        for (int q = 0; q < 5; ++q) {
            v[q] = c4[q];
            sum += (int)((v[q].x & 0xFFFFu) + (v[q].x >> 16))
                 + (int)((v[q].y & 0xFFFFu) + (v[q].y >> 16))
                 + (int)((v[q].z & 0xFFFFu) + (v[q].z >> 16))
                 + (int)((v[q].w & 0xFFFFu) + (v[q].w >> 16));
        }
        sd[t] = sum;
        __syncthreads();
#pragma unroll
        for (int off = 1; off < 256; off <<= 1) {
            int add = (t >= off) ? sd[t - off] : 0;
            __syncthreads();
            sd[t] += add;
            __syncthreads();
        }
        int run = sd[t] - sum;                // exclusive prefix at this thread
        const uint4* pb4 = (const uint4*)(pbase2w + (size_t)b * RSW) + t * 5;
        const int base = t * 40;
#pragma unroll
        for (int q = 0; q < 5; ++q) {
            uint4 pb = pb4[q];
            unsigned cw[4] = {v[q].x, v[q].y, v[q].z, v[q].w};
            unsigned pw[4] = {pb.x, pb.y, pb.z, pb.w};
#pragma unroll
            for (int u = 0; u < 4; ++u) {
                int idx = base + q * 8 + u * 2;
                int c0 = (int)(cw[u] & 0xFFFFu), c1 = (int)(cw[u] >> 16);
                cur[idx] = run + (int)(pw[u] & 0xFFFFu);
                if (b == 0 && idx < N) offs[idx] = run;
                run += c0;
                cur[idx + 1] = run + (int)(pw[u] >> 16);
                if (b == 0 && idx + 1 < N) offs[idx + 1] = run;
                run += c1;
            }
        }
        if (b == 0 && t == 255) offs[N] = run;
    }
    __syncthreads();

    // ---- placement: preload all edge pairs, then atomic+store sweep ----
    const int lo = b * perB;
    const int hi = min(lo + perB, E);
    int se[10], te[10];
#pragma unroll
    for (int k = 0; k < 10; ++k) {
        int i = lo + t + k * 256;
        te[k] = -1;
        if (i < hi) {
            if (e64) {
                se[k] = ((const int2*)e32)[(size_t)i].x;
                te[k] = ((const int2*)e32)[(size_t)E + i].x;
            } else {
                se[k] = e32[i];
                te[k] = e32[(size_t)E + i];
            }
        }
    }
#pragma unroll
    for (int k = 0; k < 10; ++k) {
        if (te[k] >= 0) {
            int pos = atomicAdd(&cur[te[k]], 1);   // LDS atomic
            sorted_src[pos] = se[k];
        }
    }
    for (int i = lo + t + 10 * 256; i < hi; i += 256) {   // tail (unused at E=640k)
        int s, tg;
        if (e64) { s = ((const int2*)e32)[(size_t)i].x; tg = ((const int2*)e32)[(size_t)E + i].x; }
        else     { s = e32[i];                           tg = e32[(size_t)E + i]; }
        int pos = atomicAdd(&cur[tg], 1);
        sorted_src[pos] = s;
    }
}

// Kernel 4: one WAVE per node. Lane l owns column pair (2l, 2l+1) — both in
// head l>>3 — gathered as ONE packed bf16x2 4B load per edge. 8 independent
// gather chains + 8-wide index prefetch. Numerator and denominator accumulate
// in registers; skip+bias epilogue.
__global__ __launch_bounds__(64) void k_aggregate(
    const int* __restrict__ offs, const int* __restrict__ sorted_src,
    const float* __restrict__ s_src, const float* __restrict__ s_tgt,
    const unsigned short* __restrict__ projb, const unsigned short* __restrict__ skipb,
    const void* __restrict__ bias, void* __restrict__ out,
    const unsigned* __restrict__ x32)
{
    const bool bf16 = wave_bf16(x32);
    const int n = blockIdx.x, l = threadIdx.x;
    const int start = offs[n], end = offs[n + 1];
    const int h = l >> 3;
    const int c2 = l * 2;
    const float st = s_tgt[(size_t)n * NH + h];

    float ae[8], ao[8], d[8];
#pragma unroll
    for (int k = 0; k < 8; ++k) { ae[k] = 0.f; ao[k] = 0.f; d[k] = 0.f; }

    const int cnt8 = (end - start) >> 3;
    int e = start;
    if (cnt8 > 0) {
        int idx[8];
#pragma unroll
        for (int k = 0; k < 8; ++k) idx[k] = sorted_src[e + k];
        for (int g = 0; g < cnt8; ++g) {
            int cu[8];
#pragma unroll
            for (int k = 0; k < 8; ++k) cu[k] = idx[k];
            e += 8;
            if (g + 1 < cnt8) {               // wave-uniform prefetch
#pragma unroll
                for (int k = 0; k < 8; ++k) idx[k] = sorted_src[e + k];
            }
            unsigned p[8];
#pragma unroll
            for (int k = 0; k < 8; ++k)
                p[k] = *(const unsigned*)(projb + (size_t)cu[k] * FIN + c2);
            float w[8];
#pragma unroll
            for (int k = 0; k < 8; ++k)
                w[k] = escore(s_src[(size_t)cu[k] * NH + h], st);
#pragma unroll
            for (int k = 0; k < 8; ++k) {
                ae[k] += w[k] * bflo(p[k]);
                ao[k] += w[k] * bfhi(p[k]);
                d[k]  += w[k];
            }
        }
    }
    for (; e < end; ++e) {
        int s = sorted_src[e];
        float w = escore(s_src[(size_t)s * NH + h], st);
        unsigned p = *(const unsigned*)(projb + (size_t)s * FIN + c2);
        ae[0] += w * bflo(p); ao[0] += w * bfhi(p); d[0] += w;
    }

    float num_e = ((ae[0] + ae[1]) + (ae[2] + ae[3])) + ((ae[4] + ae[5]) + (ae[6] + ae[7]));
    float num_o = ((ao[0] + ao[1]) + (ao[2] + ao[3])) + ((ao[4] + ao[5]) + (ao[6] + ao[7]));
    float den   = ((d[0] + d[1]) + (d[2] + d[3])) + ((d[4] + d[5]) + (d[6] + d[7]));
    float inv = 1.f / (den + 1e-16f);
    unsigned skp = *(const unsigned*)(skipb + (size_t)n * FIN + c2);
    float be, bo;
    if (bf16) {
        unsigned bb = *(const unsigned*)((const unsigned short*)bias + c2);
        be = bflo(bb); bo = bfhi(bb);
    } else {
        float2 b2 = *(const float2*)((const float*)bias + c2);
        be = b2.x; bo = b2.y;
    }
    float oe = num_e * inv + bflo(skp) + be;
    float oo = num_o * inv + bfhi(skp) + bo;
    if (bf16) {
        unsigned pr = ((unsigned)(unsigned short)f2bf(oo) << 16)
                    | (unsigned)(unsigned short)f2bf(oe);
        ((unsigned*)out)[((size_t)n * FIN + c2) >> 1] = pr;
    } else {
        float2 o2; o2.x = oe; o2.y = oo;
        *(float2*)((float*)out + (size_t)n * FIN + c2) = o2;
    }
}

extern "C" void kernel_launch(void* const* d_in, const int* in_sizes, int n_in,
                              void* d_out, int out_size, void* d_ws, size_t ws_size,
                              hipStream_t stream)
{
    const void* x    = d_in[0];
    const int* edges = (const int*)d_in[1];
    const void* Wp   = d_in[2];
    const void* Ws   = d_in[3];
    const void* ssw  = d_in[4];
    const void* stw  = d_in[5];
    const void* bias = d_in[6];

    const int N = in_sizes[0] / FIN;   // 10000
    const int E = in_sizes[1] / 2;     // 640000

    // workspace layout (256 B aligned allocations)
    char* wp = (char*)d_ws;
    auto takeB = [&wp](size_t bytes) {
        char* p = wp;
        wp += (bytes + 255) & ~(size_t)255;
        return p;
    };
    unsigned short* projb = (unsigned short*)takeB((size_t)N * FIN * 2);
    unsigned short* skipb = (unsigned short*)takeB((size_t)N * FIN * 2);
    float* s_src      = (float*)takeB((size_t)N * NH * 4);
    float* s_tgt      = (float*)takeB((size_t)N * NH * 4);
    int* sorted_src   = (int*)takeB((size_t)E * 4);
    int* offs         = (int*)takeB((size_t)(N + 8) * 4);
    unsigned* cnt2w   = (unsigned*)takeB((size_t)RSW * 4);
    unsigned* hist2w  = (unsigned*)takeB((size_t)HB * RSW * 4);
    unsigned* pbase2w = (unsigned*)takeB((size_t)HB * RSW * 4);

    const int halfTiles = (N + 15) / 16;         // 625
    const int tiles     = 2 * halfTiles;         // 1250
    const int gemmBlks  = (tiles + 3) / 4;       // 313
    const int csBlocks  = (RSW + 255) / 256;     // 20
    const int perB      = (E + HB - 1) / HB;     // 2500

    k_hist<<<HB, 256, 0, stream>>>(edges, hist2w, N, E, perB);
    k_gemmscan<<<csBlocks + gemmBlks, 256, 0, stream>>>(
        x, Wp, Ws, ssw, stw, projb, skipb, s_src, s_tgt,
        hist2w, pbase2w, cnt2w, N, tiles, halfTiles, csBlocks);
    k_place<<<HB, 256, 0, stream>>>(edges, cnt2w, pbase2w, offs, sorted_src, N, E, perB);
    k_aggregate<<<N, 64, 0, stream>>>(offs, sorted_src, s_src, s_tgt, projb,
                                      skipb, bias, d_out, (const unsigned*)x);
}